// Round 17
// baseline (194.551 us; speedup 1.0000x reference)
//
#include <hip/hip_runtime.h>
#include <hip/hip_bf16.h>

// Problem dims (fixed by reference): E=8, D=2048, B=4096, 3 layers.
#define MDIM 4096
#define NDIM 2048
#define KDIM 2048
#define KTILES 32          // K / 64
#define PER_LAYER 4194304  // 2048*2048

typedef __attribute__((ext_vector_type(8))) short bf16x8;   // 8 bf16 (4 VGPRs)
typedef __attribute__((ext_vector_type(4))) float f32x4;    // MFMA accumulator

__device__ __forceinline__ unsigned short f2bf(float f) {
    unsigned u = __builtin_bit_cast(unsigned, f);
    u += 0x7FFFu + ((u >> 16) & 1u);        // round-to-nearest-even
    return (unsigned short)(u >> 16);
}

// fast ELU negative branch: exp(v)-1 via v_exp_f32; bf16 output rounding
// (2^-8 rel) dwarfs the exp approximation error vs expm1f. (r15: +7.4us)
__device__ __forceinline__ float fast_elu_neg(float v) {
    return __expf(v) - 1.0f;
}

// ---------------------------------------------------------------------------
// Kernel 1: blend layer-0 experts + convert x to bf16 (W1/W2 blend is fused
// into the GEMM kernels). Reads 134MB W0 + 32MB x -> ~30us HBM-bound.
// ---------------------------------------------------------------------------
__global__ __launch_bounds__(256) void blend0_kernel(
    const float* __restrict__ W, const float* __restrict__ cb,
    const float* __restrict__ x,
    unsigned short* __restrict__ wb, unsigned short* __restrict__ xb)
{
    float c[8];
#pragma unroll
    for (int e = 0; e < 8; ++e) c[e] = cb[e];
    const unsigned wtotal4 = PER_LAYER >> 2;        // 1,048,576 float4 units
    const unsigned xtotal4 = 2097152u;              // 8M / 4
    const unsigned total = wtotal4 + xtotal4;
    unsigned stride = gridDim.x * blockDim.x;
    for (unsigned i = blockIdx.x * blockDim.x + threadIdx.x; i < total; i += stride) {
        if (i < wtotal4) {
            unsigned off = i << 2;
            const float* base = W + off;
            float4 s = make_float4(0.f, 0.f, 0.f, 0.f);
#pragma unroll
            for (int e = 0; e < 8; ++e) {
                float4 v = *(const float4*)(base + (size_t)e * PER_LAYER);
                s.x += c[e] * v.x; s.y += c[e] * v.y;
                s.z += c[e] * v.z; s.w += c[e] * v.w;
            }
            ushort4 o;
            o.x = f2bf(s.x); o.y = f2bf(s.y); o.z = f2bf(s.z); o.w = f2bf(s.w);
            *(ushort4*)(wb + off) = o;
        } else {
            unsigned j = (i - wtotal4) << 2;
            float4 v = *(const float4*)(x + j);
            ushort4 o;
            o.x = f2bf(v.x); o.y = f2bf(v.y); o.z = f2bf(v.z); o.w = f2bf(v.w);
            *(ushort4*)(xb + j) = o;
        }
    }
}

// ---------------------------------------------------------------------------
// Kernel 2: r7 GEMM (256x128 tile, 3-buf LDS 144KB, 2-tile-deep prefetch,
// 1 barrier per K-tile) + OPTIONAL fused blend of the NEXT layer's weights.
//   C[M,N] = A[M,K] * Bw[N,K]^T + bias, optional ELU;  wbNext = sum_e c_e W_e.
// grid = 256 blocks (all CUs), 512 threads = 8 waves (4M x 2N), wave 64x64.
// r16: s_setprio removed (m190: null-to-negative on lockstep GEMM).
// r17: STAGE issued BEFORE ds_reads (T3 recipe ordering) — loads in flight
// earlier, shrinking the end-of-iter VMC(6) wait. WAR unchanged: stage
// target buf (t+2)%3 readers finished before the end-of-(t-1) barrier.
// Blend: on iters t=0,3,..,21 each thread blends ONE float4 of W_next
// (8x16B loads + 1 store = 9 vmem ops) issued AFTER the end-of-iter barrier.
// vmcnt ledger (FIFO, per wave):
//   t%3==0: outstanding stage(t+1)6 + stage(t+2)6 -> VMC(6) drains t+1; blend after.
//   t%3==1: outstanding stage(t+2)6 + blend9 + stage(t+3)6 -> VMC(15) drains t+2.
//   t%3==2: VMC(6) (also drains the old blend ops).
// BLEND=0 uses VMC(6) everywhere.
// ---------------------------------------------------------------------------
#define BARR() do { asm volatile("" ::: "memory"); __builtin_amdgcn_s_barrier(); asm volatile("" ::: "memory"); } while (0)
#define VMC_IMPL(N) asm volatile("s_waitcnt vmcnt(" #N ")" ::: "memory")
#define VMC(N) VMC_IMPL(N)

template<int ACT, typename OutT, int BLEND>
__global__ __launch_bounds__(512, 2) void gemm_fused(
    const unsigned short* __restrict__ A,   // M x K bf16 bits
    const unsigned short* __restrict__ Bw,  // N x K bf16 bits
    const float* __restrict__ bias,         // N
    OutT* __restrict__ C,                   // M x N
    const float* __restrict__ Wnext,        // 8 x 2048 x 2048 f32 (or null)
    const float* __restrict__ cb,           // (8,) blend coeffs (or null)
    unsigned short* __restrict__ wbNext)    // 2048 x 2048 bf16 out (or null)
{
    __shared__ __align__(16) unsigned short lds[73728];   // 144 KB
    char* ldsc = (char*)lds;

    const int tid = threadIdx.x;
    const int wid = tid >> 6;
    const int lane = tid & 63;
    const int wr = wid >> 1;      // 0..3 (M)
    const int wc = wid & 1;       // 0..1 (N)

    // blend coeffs: load + fence BEFORE any counted vmem ops.
    float cw[8];
    if (BLEND) {
#pragma unroll
        for (int e = 0; e < 8; ++e) cw[e] = cb[e];
        VMC(0);
    }

    // bijective XCD-chunked swizzle: XCD k gets wg in [k*32,(k+1)*32)
    // = 2 N-panels x 16 M-tiles -> B panels (1MB) L2-resident per XCD.
    const int wg = (blockIdx.x & 7) * 32 + (blockIdx.x >> 3);
    const size_t blockM = (size_t)(wg & 15) * 256;
    const size_t blockN = (size_t)(wg >> 4) * 128;

    // ds_read addressing: swizzled 16B slot within a 128B row.
    const int sw = (lane & 7) << 4;          // (row&7)<<4; row&7 == lane&7
    const int ck = (lane >> 4) << 4;         // k-slot byte base
    const int rAb = wr * 64 + (lane & 15);   // + m*16
    const int rBb = wc * 64 + (lane & 15);   // + n*16

    // staging: thread t writes LDS bytes [tid*16, tid*16+16) of an 8KB
    // 64-row stage; source column pre-XORed (both-sides swizzle).
    const int srow = tid >> 3;                       // 0..63
    const int scol = ((tid & 7) ^ (srow & 7)) << 3;  // element offset
    const unsigned short* aStage = A + (blockM + srow) * KDIM + scol;
    const unsigned short* bStage = Bw + (blockN + srow) * KDIM + scol;

#define STAGE_AS(BUF, S, KT) do { \
    const unsigned short* g_ = aStage + (size_t)(S) * 64 * KDIM + (size_t)(KT) * 64; \
    __builtin_amdgcn_global_load_lds((const __attribute__((address_space(1))) void*)g_, \
        (__attribute__((address_space(3))) void*)(ldsc + (BUF) * 49152 + (S) * 8192 + tid * 16), \
        16, 0, 0); \
} while (0)

#define STAGE_BS(BUF, S, KT) do { \
    const unsigned short* g_ = bStage + (size_t)(S) * 64 * KDIM + (size_t)(KT) * 64; \
    __builtin_amdgcn_global_load_lds((const __attribute__((address_space(1))) void*)g_, \
        (__attribute__((address_space(3))) void*)(ldsc + (BUF) * 49152 + 32768 + (S) * 8192 + tid * 16), \
        16, 0, 0); \
} while (0)

#define RD_A(BUF, M, KK) \
    (*(const bf16x8*)(ldsc + (BUF) * 49152 + ((rAb + (M) * 16)) * 128 + (((KK) * 64 + ck) ^ sw)))
#define RD_B(BUF, N, KK) \
    (*(const bf16x8*)(ldsc + (BUF) * 49152 + 32768 + (rBb + (N) * 16) * 128 + (((KK) * 64 + ck) ^ sw)))

    f32x4 acc[4][4];
#pragma unroll
    for (int m = 0; m < 4; ++m)
#pragma unroll
        for (int n = 0; n < 4; ++n) acc[m][n] = (f32x4){0.f, 0.f, 0.f, 0.f};

    // One GEMM K-iteration: stage tile t+2 FIRST (loads in flight early),
    // then ds_read tile t from buf `cur`, MFMA, counted wait, barrier.
#define GEMM_ITER(T, WAITER) do { \
    int stb_ = cur + 2; if (stb_ >= 3) stb_ -= 3; \
    if ((T) + 2 < KTILES) { \
        STAGE_AS(stb_, 0, (T) + 2); STAGE_AS(stb_, 1, (T) + 2); \
        STAGE_AS(stb_, 2, (T) + 2); STAGE_AS(stb_, 3, (T) + 2); \
        STAGE_BS(stb_, 0, (T) + 2); STAGE_BS(stb_, 1, (T) + 2); \
    } \
    bf16x8 af[4][2], bfr[4][2]; \
    _Pragma("unroll") for (int m_ = 0; m_ < 4; ++m_) { \
        af[m_][0] = RD_A(cur, m_, 0); af[m_][1] = RD_A(cur, m_, 1); } \
    _Pragma("unroll") for (int n_ = 0; n_ < 4; ++n_) { \
        bfr[n_][0] = RD_B(cur, n_, 0); bfr[n_][1] = RD_B(cur, n_, 1); } \
    _Pragma("unroll") for (int kk_ = 0; kk_ < 2; ++kk_) \
    _Pragma("unroll") for (int m_ = 0; m_ < 4; ++m_) \
    _Pragma("unroll") for (int n_ = 0; n_ < 4; ++n_) \
        acc[m_][n_] = __builtin_amdgcn_mfma_f32_16x16x32_bf16( \
            af[m_][kk_], bfr[n_][kk_], acc[m_][n_], 0, 0, 0); \
    WAITER; \
    BARR(); \
    cur = cur + 1; if (cur >= 3) cur = 0; \
} while (0)

    // one blend chunk: this thread blends float4 #(G*131072 + bid*512 + tid)
#define BLEND_STEP(G) do { \
    const unsigned idx_ = (unsigned)(G) * 131072u + (unsigned)blockIdx.x * 512u + (unsigned)tid; \
    const unsigned off_ = idx_ << 2; \
    const float* bs_ = Wnext + off_; \
    float4 s_ = make_float4(0.f, 0.f, 0.f, 0.f); \
    _Pragma("unroll") for (int e_ = 0; e_ < 8; ++e_) { \
        float4 v_ = *(const float4*)(bs_ + (size_t)e_ * PER_LAYER); \
        s_.x += cw[e_] * v_.x; s_.y += cw[e_] * v_.y; \
        s_.z += cw[e_] * v_.z; s_.w += cw[e_] * v_.w; } \
    ushort4 o_; \
    o_.x = f2bf(s_.x); o_.y = f2bf(s_.y); o_.z = f2bf(s_.z); o_.w = f2bf(s_.w); \
    *(ushort4*)(wbNext + off_) = o_; \
} while (0)

    // ---- prologue: tile0 -> buf0, tile1 -> buf1 ----
    STAGE_AS(0, 0, 0); STAGE_AS(0, 1, 0); STAGE_AS(0, 2, 0); STAGE_AS(0, 3, 0);
    STAGE_BS(0, 0, 0); STAGE_BS(0, 1, 0);
    STAGE_AS(1, 0, 1); STAGE_AS(1, 1, 1); STAGE_AS(1, 2, 1); STAGE_AS(1, 3, 1);
    STAGE_BS(1, 0, 1); STAGE_BS(1, 1, 1);
    VMC(6);                       // tile0 landed; tile1's 6 in flight
    BARR();

    int cur = 0;
    if (BLEND) {
#pragma unroll 1
        for (int g = 0; g < 8; ++g) {
            GEMM_ITER(3 * g, VMC(6));
            BLEND_STEP(g);                     // 9 vmem ops at start of iter 3g+1
            GEMM_ITER(3 * g + 1, VMC(15));     // drain S(3g+2); keep blend+S(3g+3)
            GEMM_ITER(3 * g + 2, VMC(6));      // drains blend + S(3g+3)
        }
#pragma unroll 1
        for (int t = 24; t < 30; ++t) GEMM_ITER(t, VMC(6));
    } else {
#pragma unroll 1
        for (int t = 0; t < 30; ++t) GEMM_ITER(t, VMC(6));
    }
    GEMM_ITER(30, VMC(0));        // stages nothing; drains S(31)
    GEMM_ITER(31, VMC(0));        // final tile

    // ---- epilogue: C/D layout col=lane&15 (N), row=(lane>>4)*4+reg (M) ----
    const int crow = (lane >> 4) * 4;
    const int ccol = lane & 15;
#pragma unroll
    for (int m = 0; m < 4; ++m)
#pragma unroll
        for (int n = 0; n < 4; ++n) {
            const size_t col = blockN + wc * 64 + n * 16 + ccol;
            const float bv = bias[col];
#pragma unroll
            for (int r = 0; r < 4; ++r) {
                const size_t row = blockM + wr * 64 + m * 16 + crow + r;
                float v = acc[m][n][r] + bv;
                if (ACT) v = v > 0.f ? v : fast_elu_neg(v);
                if constexpr (sizeof(OutT) == 2) {
                    C[row * NDIM + col] = (OutT)f2bf(v);
                } else {
                    C[row * NDIM + col] = (OutT)v;
                }
            }
        }
#undef STAGE_AS
#undef STAGE_BS
#undef RD_A
#undef RD_B
#undef GEMM_ITER
#undef BLEND_STEP
}

// ---------------------------------------------------------------------------
// Launch: blend0+convert, then 3 chained GEMMs; GEMM0 blends W1, GEMM1
// blends W2 (overlapped with compute), GEMM2 plain.
// Workspace (ushort units): wb[3*PER_LAYER] weights, xb[8388608], y0[8388608].
// ---------------------------------------------------------------------------
extern "C" void kernel_launch(void* const* d_in, const int* in_sizes, int n_in,
                              void* d_out, int out_size, void* d_ws, size_t ws_size,
                              hipStream_t stream) {
    const float* blendw = (const float*)d_in[0];   // (8,)
    const float* x      = (const float*)d_in[1];   // (4096, 2048)
    const float* W      = (const float*)d_in[2];   // (3, 8, 2048, 2048)
    const float* Bb     = (const float*)d_in[3];   // (3, 2048)
    float* out = (float*)d_out;                    // (4096, 2048) f32

    unsigned short* wb0 = (unsigned short*)d_ws;
    unsigned short* wb1 = wb0 + PER_LAYER;
    unsigned short* wb2 = wb1 + PER_LAYER;
    unsigned short* xb  = wb2 + PER_LAYER;
    unsigned short* y0  = xb + 8388608;
    unsigned short* y1  = xb;   // reuse: xb dead after GEMM0

    blend0_kernel<<<2048, 256, 0, stream>>>(W, blendw, x, wb0, xb);

    const int grid = (MDIM / 256) * (NDIM / 128);    // 256 blocks = all CUs
    gemm_fused<1, unsigned short, 1><<<grid, 512, 0, stream>>>(
        xb, wb0, Bb,        y0,  W + (size_t)8 * PER_LAYER,  blendw, wb1);
    gemm_fused<1, unsigned short, 1><<<grid, 512, 0, stream>>>(
        y0, wb1, Bb + 2048, y1,  W + (size_t)16 * PER_LAYER, blendw, wb2);
    gemm_fused<0, float, 0><<<grid, 512, 0, stream>>>(
        y1, wb2, Bb + 4096, out, nullptr, nullptr, nullptr);
}

// Round 18
// 191.312 us; speedup vs baseline: 1.0169x; 1.0169x over previous
//
#include <hip/hip_runtime.h>
#include <hip/hip_bf16.h>

// Problem dims (fixed by reference): E=8, D=2048, B=4096, 3 layers.
#define MDIM 4096
#define NDIM 2048
#define KDIM 2048
#define KTILES 32          // K / 64
#define PER_LAYER 4194304  // 2048*2048

typedef __attribute__((ext_vector_type(8))) short bf16x8;   // 8 bf16 (4 VGPRs)
typedef __attribute__((ext_vector_type(4))) float f32x4;    // MFMA accumulator

__device__ __forceinline__ unsigned short f2bf(float f) {
    unsigned u = __builtin_bit_cast(unsigned, f);
    u += 0x7FFFu + ((u >> 16) & 1u);        // round-to-nearest-even
    return (unsigned short)(u >> 16);
}

// fast ELU negative branch: exp(v)-1 via v_exp_f32; bf16 output rounding
// (2^-8 rel) dwarfs the exp approximation error vs expm1f. (r15: +7.4us)
__device__ __forceinline__ float fast_elu_neg(float v) {
    return __expf(v) - 1.0f;
}

// ---------------------------------------------------------------------------
// Kernel 1: blend layer-0 experts + convert x to bf16 (W1/W2 blend is fused
// into the GEMM kernels). Reads 134MB W0 + 32MB x -> ~30us HBM-bound.
// ---------------------------------------------------------------------------
__global__ __launch_bounds__(256) void blend0_kernel(
    const float* __restrict__ W, const float* __restrict__ cb,
    const float* __restrict__ x,
    unsigned short* __restrict__ wb, unsigned short* __restrict__ xb)
{
    float c[8];
#pragma unroll
    for (int e = 0; e < 8; ++e) c[e] = cb[e];
    const unsigned wtotal4 = PER_LAYER >> 2;        // 1,048,576 float4 units
    const unsigned xtotal4 = 2097152u;              // 8M / 4
    const unsigned total = wtotal4 + xtotal4;
    unsigned stride = gridDim.x * blockDim.x;
    for (unsigned i = blockIdx.x * blockDim.x + threadIdx.x; i < total; i += stride) {
        if (i < wtotal4) {
            unsigned off = i << 2;
            const float* base = W + off;
            float4 s = make_float4(0.f, 0.f, 0.f, 0.f);
#pragma unroll
            for (int e = 0; e < 8; ++e) {
                float4 v = *(const float4*)(base + (size_t)e * PER_LAYER);
                s.x += c[e] * v.x; s.y += c[e] * v.y;
                s.z += c[e] * v.z; s.w += c[e] * v.w;
            }
            ushort4 o;
            o.x = f2bf(s.x); o.y = f2bf(s.y); o.z = f2bf(s.z); o.w = f2bf(s.w);
            *(ushort4*)(wb + off) = o;
        } else {
            unsigned j = (i - wtotal4) << 2;
            float4 v = *(const float4*)(x + j);
            ushort4 o;
            o.x = f2bf(v.x); o.y = f2bf(v.y); o.z = f2bf(v.z); o.w = f2bf(v.w);
            *(ushort4*)(xb + j) = o;
        }
    }
}

// ---------------------------------------------------------------------------
// Kernel 2: r7 GEMM (256x128 tile, 3-buf LDS 144KB, 2-tile-deep prefetch,
// 1 barrier per K-tile) + OPTIONAL fused blend of the NEXT layer's weights.
//   C[M,N] = A[M,K] * Bw[N,K]^T + bias, optional ELU;  wbNext = sum_e c_e W_e.
// grid = 256 blocks (all CUs), 512 threads = 8 waves (4M x 2N), wave 64x64.
// r16: s_setprio removed (m190: null-to-negative on lockstep GEMM; +5.2us).
// r17's stage-first ordering reverted (-2.8us regression): ds_reads feed the
// MFMA critical path and must issue first; compiler handles the rest.
// Blend: on iters t=0,3,..,21 each thread blends ONE float4 of W_next
// (8x16B loads + 1 store = 9 vmem ops) issued AFTER the end-of-iter barrier.
// vmcnt ledger (FIFO, per wave):
//   t%3==0: outstanding stage(t+1)6 + stage(t+2)6 -> VMC(6) drains t+1; blend after.
//   t%3==1: outstanding stage(t+2)6 + blend9 + stage(t+3)6 -> VMC(15) drains t+2.
//   t%3==2: VMC(6) (also drains the old blend ops).
// BLEND=0 uses VMC(6) everywhere.
// WAR: stage target buf (t+2)%3 last read iter t-1, barrier-separated.
// ---------------------------------------------------------------------------
#define BARR() do { asm volatile("" ::: "memory"); __builtin_amdgcn_s_barrier(); asm volatile("" ::: "memory"); } while (0)
#define VMC_IMPL(N) asm volatile("s_waitcnt vmcnt(" #N ")" ::: "memory")
#define VMC(N) VMC_IMPL(N)

template<int ACT, typename OutT, int BLEND>
__global__ __launch_bounds__(512, 2) void gemm_fused(
    const unsigned short* __restrict__ A,   // M x K bf16 bits
    const unsigned short* __restrict__ Bw,  // N x K bf16 bits
    const float* __restrict__ bias,         // N
    OutT* __restrict__ C,                   // M x N
    const float* __restrict__ Wnext,        // 8 x 2048 x 2048 f32 (or null)
    const float* __restrict__ cb,           // (8,) blend coeffs (or null)
    unsigned short* __restrict__ wbNext)    // 2048 x 2048 bf16 out (or null)
{
    __shared__ __align__(16) unsigned short lds[73728];   // 144 KB
    char* ldsc = (char*)lds;

    const int tid = threadIdx.x;
    const int wid = tid >> 6;
    const int lane = tid & 63;
    const int wr = wid >> 1;      // 0..3 (M)
    const int wc = wid & 1;       // 0..1 (N)

    // blend coeffs: load + fence BEFORE any counted vmem ops.
    float cw[8];
    if (BLEND) {
#pragma unroll
        for (int e = 0; e < 8; ++e) cw[e] = cb[e];
        VMC(0);
    }

    // bijective XCD-chunked swizzle: XCD k gets wg in [k*32,(k+1)*32)
    // = 2 N-panels x 16 M-tiles -> B panels (1MB) L2-resident per XCD.
    const int wg = (blockIdx.x & 7) * 32 + (blockIdx.x >> 3);
    const size_t blockM = (size_t)(wg & 15) * 256;
    const size_t blockN = (size_t)(wg >> 4) * 128;

    // ds_read addressing: swizzled 16B slot within a 128B row.
    const int sw = (lane & 7) << 4;          // (row&7)<<4; row&7 == lane&7
    const int ck = (lane >> 4) << 4;         // k-slot byte base
    const int rAb = wr * 64 + (lane & 15);   // + m*16
    const int rBb = wc * 64 + (lane & 15);   // + n*16

    // staging: thread t writes LDS bytes [tid*16, tid*16+16) of an 8KB
    // 64-row stage; source column pre-XORed (both-sides swizzle).
    const int srow = tid >> 3;                       // 0..63
    const int scol = ((tid & 7) ^ (srow & 7)) << 3;  // element offset
    const unsigned short* aStage = A + (blockM + srow) * KDIM + scol;
    const unsigned short* bStage = Bw + (blockN + srow) * KDIM + scol;

#define STAGE_AS(BUF, S, KT) do { \
    const unsigned short* g_ = aStage + (size_t)(S) * 64 * KDIM + (size_t)(KT) * 64; \
    __builtin_amdgcn_global_load_lds((const __attribute__((address_space(1))) void*)g_, \
        (__attribute__((address_space(3))) void*)(ldsc + (BUF) * 49152 + (S) * 8192 + tid * 16), \
        16, 0, 0); \
} while (0)

#define STAGE_BS(BUF, S, KT) do { \
    const unsigned short* g_ = bStage + (size_t)(S) * 64 * KDIM + (size_t)(KT) * 64; \
    __builtin_amdgcn_global_load_lds((const __attribute__((address_space(1))) void*)g_, \
        (__attribute__((address_space(3))) void*)(ldsc + (BUF) * 49152 + 32768 + (S) * 8192 + tid * 16), \
        16, 0, 0); \
} while (0)

#define RD_A(BUF, M, KK) \
    (*(const bf16x8*)(ldsc + (BUF) * 49152 + ((rAb + (M) * 16)) * 128 + (((KK) * 64 + ck) ^ sw)))
#define RD_B(BUF, N, KK) \
    (*(const bf16x8*)(ldsc + (BUF) * 49152 + 32768 + (rBb + (N) * 16) * 128 + (((KK) * 64 + ck) ^ sw)))

    f32x4 acc[4][4];
#pragma unroll
    for (int m = 0; m < 4; ++m)
#pragma unroll
        for (int n = 0; n < 4; ++n) acc[m][n] = (f32x4){0.f, 0.f, 0.f, 0.f};

    // One GEMM K-iteration: reads tile in buf `cur`, stages tile t+2 into
    // buf (cur+2)%3, MFMAs, then WAITER, barrier, advances cur.
#define GEMM_ITER(T, WAITER) do { \
    int stb_ = cur + 2; if (stb_ >= 3) stb_ -= 3; \
    bf16x8 af[4][2], bfr[4][2]; \
    _Pragma("unroll") for (int m_ = 0; m_ < 4; ++m_) { \
        af[m_][0] = RD_A(cur, m_, 0); af[m_][1] = RD_A(cur, m_, 1); } \
    _Pragma("unroll") for (int n_ = 0; n_ < 4; ++n_) { \
        bfr[n_][0] = RD_B(cur, n_, 0); bfr[n_][1] = RD_B(cur, n_, 1); } \
    if ((T) + 2 < KTILES) { \
        STAGE_AS(stb_, 0, (T) + 2); STAGE_AS(stb_, 1, (T) + 2); \
        STAGE_AS(stb_, 2, (T) + 2); STAGE_AS(stb_, 3, (T) + 2); \
        STAGE_BS(stb_, 0, (T) + 2); STAGE_BS(stb_, 1, (T) + 2); \
    } \
    _Pragma("unroll") for (int kk_ = 0; kk_ < 2; ++kk_) \
    _Pragma("unroll") for (int m_ = 0; m_ < 4; ++m_) \
    _Pragma("unroll") for (int n_ = 0; n_ < 4; ++n_) \
        acc[m_][n_] = __builtin_amdgcn_mfma_f32_16x16x32_bf16( \
            af[m_][kk_], bfr[n_][kk_], acc[m_][n_], 0, 0, 0); \
    WAITER; \
    BARR(); \
    cur = cur + 1; if (cur >= 3) cur = 0; \
} while (0)

    // one blend chunk: this thread blends float4 #(G*131072 + bid*512 + tid)
#define BLEND_STEP(G) do { \
    const unsigned idx_ = (unsigned)(G) * 131072u + (unsigned)blockIdx.x * 512u + (unsigned)tid; \
    const unsigned off_ = idx_ << 2; \
    const float* bs_ = Wnext + off_; \
    float4 s_ = make_float4(0.f, 0.f, 0.f, 0.f); \
    _Pragma("unroll") for (int e_ = 0; e_ < 8; ++e_) { \
        float4 v_ = *(const float4*)(bs_ + (size_t)e_ * PER_LAYER); \
        s_.x += cw[e_] * v_.x; s_.y += cw[e_] * v_.y; \
        s_.z += cw[e_] * v_.z; s_.w += cw[e_] * v_.w; } \
    ushort4 o_; \
    o_.x = f2bf(s_.x); o_.y = f2bf(s_.y); o_.z = f2bf(s_.z); o_.w = f2bf(s_.w); \
    *(ushort4*)(wbNext + off_) = o_; \
} while (0)

    // ---- prologue: tile0 -> buf0, tile1 -> buf1 ----
    STAGE_AS(0, 0, 0); STAGE_AS(0, 1, 0); STAGE_AS(0, 2, 0); STAGE_AS(0, 3, 0);
    STAGE_BS(0, 0, 0); STAGE_BS(0, 1, 0);
    STAGE_AS(1, 0, 1); STAGE_AS(1, 1, 1); STAGE_AS(1, 2, 1); STAGE_AS(1, 3, 1);
    STAGE_BS(1, 0, 1); STAGE_BS(1, 1, 1);
    VMC(6);                       // tile0 landed; tile1's 6 in flight
    BARR();

    int cur = 0;
    if (BLEND) {
#pragma unroll 1
        for (int g = 0; g < 8; ++g) {
            GEMM_ITER(3 * g, VMC(6));
            BLEND_STEP(g);                     // 9 vmem ops at start of iter 3g+1
            GEMM_ITER(3 * g + 1, VMC(15));     // drain S(3g+2); keep blend+S(3g+3)
            GEMM_ITER(3 * g + 2, VMC(6));      // drains blend + S(3g+3)
        }
#pragma unroll 1
        for (int t = 24; t < 30; ++t) GEMM_ITER(t, VMC(6));
    } else {
#pragma unroll 1
        for (int t = 0; t < 30; ++t) GEMM_ITER(t, VMC(6));
    }
    GEMM_ITER(30, VMC(0));        // stages nothing; drains S(31)
    GEMM_ITER(31, VMC(0));        // final tile

    // ---- epilogue: C/D layout col=lane&15 (N), row=(lane>>4)*4+reg (M) ----
    const int crow = (lane >> 4) * 4;
    const int ccol = lane & 15;
#pragma unroll
    for (int m = 0; m < 4; ++m)
#pragma unroll
        for (int n = 0; n < 4; ++n) {
            const size_t col = blockN + wc * 64 + n * 16 + ccol;
            const float bv = bias[col];
#pragma unroll
            for (int r = 0; r < 4; ++r) {
                const size_t row = blockM + wr * 64 + m * 16 + crow + r;
                float v = acc[m][n][r] + bv;
                if (ACT) v = v > 0.f ? v : fast_elu_neg(v);
                if constexpr (sizeof(OutT) == 2) {
                    C[row * NDIM + col] = (OutT)f2bf(v);
                } else {
                    C[row * NDIM + col] = (OutT)v;
                }
            }
        }
#undef STAGE_AS
#undef STAGE_BS
#undef RD_A
#undef RD_B
#undef GEMM_ITER
#undef BLEND_STEP
}

// ---------------------------------------------------------------------------
// Launch: blend0+convert, then 3 chained GEMMs; GEMM0 blends W1, GEMM1
// blends W2 (overlapped with compute), GEMM2 plain.
// Workspace (ushort units): wb[3*PER_LAYER] weights, xb[8388608], y0[8388608].
// ---------------------------------------------------------------------------
extern "C" void kernel_launch(void* const* d_in, const int* in_sizes, int n_in,
                              void* d_out, int out_size, void* d_ws, size_t ws_size,
                              hipStream_t stream) {
    const float* blendw = (const float*)d_in[0];   // (8,)
    const float* x      = (const float*)d_in[1];   // (4096, 2048)
    const float* W      = (const float*)d_in[2];   // (3, 8, 2048, 2048)
    const float* Bb     = (const float*)d_in[3];   // (3, 2048)
    float* out = (float*)d_out;                    // (4096, 2048) f32

    unsigned short* wb0 = (unsigned short*)d_ws;
    unsigned short* wb1 = wb0 + PER_LAYER;
    unsigned short* wb2 = wb1 + PER_LAYER;
    unsigned short* xb  = wb2 + PER_LAYER;
    unsigned short* y0  = xb + 8388608;
    unsigned short* y1  = xb;   // reuse: xb dead after GEMM0

    blend0_kernel<<<2048, 256, 0, stream>>>(W, blendw, x, wb0, xb);

    const int grid = (MDIM / 256) * (NDIM / 128);    // 256 blocks = all CUs
    gemm_fused<1, unsigned short, 1><<<grid, 512, 0, stream>>>(
        xb, wb0, Bb,        y0,  W + (size_t)8 * PER_LAYER,  blendw, wb1);
    gemm_fused<1, unsigned short, 1><<<grid, 512, 0, stream>>>(
        y0, wb1, Bb + 2048, y1,  W + (size_t)16 * PER_LAYER, blendw, wb2);
    gemm_fused<0, float, 0><<<grid, 512, 0, stream>>>(
        y1, wb2, Bb + 4096, out, nullptr, nullptr, nullptr);
}